// Round 8
// baseline (624.990 us; speedup 1.0000x reference)
//
#include <hip/hip_runtime.h>
#include <hip/hip_bf16.h>
#include <math.h>

// AFNO2D: rfft2(128x128, ortho) -> blockdiag complex MLP (8 x 96) -> softshrink -> irfft2 -> +bias
// B=4, H=W=128, C=768.  ALL transforms are MFMA GEMMs against baked bf16 matrices (tables in d_ws
// after the A plane). Spectral plane in ws: packed uint per point (bf16 re | bf16 im<<16),
// A[b][pos=h*65+kw][c].
// k_mid v2: separate bf16 R/I LDS arrays for the H-DFT GEMMs (no per-read unpack VALU),
// 3-part twiddles (cos,sin,-sin) shared fwd/inv, MLP B-frags straight from L2-hot global
// (no WfL staging), LDS 53 KB, 4 barriers.

#define HD   768
#define NBLK 8
#define HH   128
#define WW   128
#define WC   65
#define NPOS (HH * WC)

constexpr float SC    = 0.08838834764831845f;      // 1/sqrt(128)
constexpr float TWOPI = 6.28318530717958647692f;

// table layout (ushort offsets from wf base)
constexpr int TM_OFF     = 0;        // H-DFT: 96 frags = part(3:cos,sin,-sin) x kot(8) x kk(4)
constexpr int TW_OFF     = 49152;    // W-rfft: 40 frags = mt(10) x kk(4)
constexpr int TWI_OFF    = 69632;    // W-irfft: 40 frags = mt(8) x kk(5)
constexpr int WF_OFF     = 90112;    // MLP: 16 (layer,n) x 72 frags (full bake)
constexpr int WF_END_U16 = 679936;   // WF_OFF + 16*72*512
constexpr size_t A_UINTS = (size_t)4 * NPOS * HD;  // 102.2 MB

typedef __attribute__((ext_vector_type(8))) short short8;
typedef __attribute__((ext_vector_type(4))) float f32x4;

#define MFMA __builtin_amdgcn_mfma_f32_16x16x32_bf16

static __device__ inline unsigned short f2bf(float f) {
  __hip_bfloat16 h = __float2bfloat16(f);
  return __builtin_bit_cast(unsigned short, h);
}
static __device__ inline unsigned int pack2(float re, float im) {
  return (unsigned int)f2bf(re) | ((unsigned int)f2bf(im) << 16);
}
static __device__ inline short8 lo8(uint4 a, uint4 b) {
  uint4 r = { (a.x & 0xffffu) | (a.y << 16), (a.z & 0xffffu) | (a.w << 16),
              (b.x & 0xffffu) | (b.y << 16), (b.z & 0xffffu) | (b.w << 16) };
  return __builtin_bit_cast(short8, r);
}
static __device__ inline short8 hi8(uint4 a, uint4 b) {
  uint4 r = { (a.x >> 16) | (a.y & 0xffff0000u), (a.z >> 16) | (a.w & 0xffff0000u),
              (b.x >> 16) | (b.y & 0xffff0000u), (b.z >> 16) | (b.w & 0xffff0000u) };
  return __builtin_bit_cast(short8, r);
}

// ================= k_prep: bake all MFMA fragment images =================
// A-frag: lane holds A[row = tile*16 + (l&15)][k = kk*32 + (l>>4)*8 + j]
// B-frag: lane holds B[k = kk*32 + (l>>4)*8 + j][col = nt*16 + (l&15)]
__global__ __launch_bounds__(256) void k_prep(const float* __restrict__ w1,
                                              const float* __restrict__ b1,
                                              const float* __restrict__ w2,
                                              const float* __restrict__ b2,
                                              unsigned short* __restrict__ wf,
                                              float* __restrict__ bpk) {
  const int blk = blockIdx.x, t = threadIdx.x;
  if (blk < 16) {                      // MLP Waug B-frags (FULL 72) + biases
    const int layer = blk >> 3, n = blk & 7;
    const float* w  = layer ? w2 : w1;
    const float* bs = layer ? b2 : b1;
    unsigned short* dst = wf + WF_OFF + (size_t)blk * (72 * 512);
    for (int e = t; e < 72 * 512; e += 256) {
      int f = e >> 9, idx = e & 511;
      int kk = f / 12, nt = f - kk * 12;
      int lane = idx >> 3, j = idx & 7;
      int k  = kk * 32 + (lane >> 4) * 8 + j;     // 0..191
      int cc = nt * 16 + (lane & 15);             // 0..191
      float v;
      if (k < 96) v = (cc < 96) ? w[(size_t)n * 9216 + k * 96 + cc]
                                : w[(size_t)(8 + n) * 9216 + k * 96 + (cc - 96)];
      else        v = (cc < 96) ? -w[(size_t)(8 + n) * 9216 + (k - 96) * 96 + cc]
                                :  w[(size_t)n * 9216 + (k - 96) * 96 + (cc - 96)];
      dst[e] = f2bf(v);
    }
    for (int c = t; c < 192; c += 256)
      bpk[blk * 192 + c] = (c < 96) ? bs[n * 96 + c] : bs[(8 + n) * 96 + (c - 96)];
  } else if (blk == 16) {              // H-DFT twiddles: 3 parts x 32 (kot*4+kk)
    for (int e = t; e < 96 * 512; e += 256) {
      int f = e >> 9, idx = e & 511;
      int part = f >> 5, rem = f & 31, kot = rem >> 2, kk = rem & 3;
      int lane = idx >> 3, j = idx & 7;
      int ko = kot * 16 + (lane & 15);
      int r  = kk * 32 + (lane >> 4) * 8 + j;     // 0..127
      float sn, cs; sincosf((TWOPI / 128.f) * (float)((ko * r) & 127), &sn, &cs);
      float v = (part == 0) ? cs : (part == 1) ? sn : -sn;
      wf[TM_OFF + (size_t)f * 512 + idx] = f2bf(v * SC);
    }
  } else if (blk == 17) {              // W-rfft matrix: rows 0..79 = re, 80..159 = im
    for (int e = t; e < 40 * 512; e += 256) {
      int f = e >> 9, idx = e & 511;
      int mt = f >> 2, kk = f & 3;
      int lane = idx >> 3, j = idx & 7;
      int row = mt * 16 + (lane & 15);
      int r   = kk * 32 + (lane >> 4) * 8 + j;    // 0..127
      int kor = (row < 80) ? row : row - 80;
      float sn, cs; sincosf((TWOPI / 128.f) * (float)((kor * r) & 127), &sn, &cs);
      wf[TW_OFF + (size_t)f * 512 + idx] = f2bf((row < 80 ? cs : -sn) * SC);
    }
  } else {                             // W-irfft matrix: K = [re 0..79 | im 0..79]
    for (int e = t; e < 40 * 512; e += 256) {
      int f = e >> 9, idx = e & 511;
      int mt = f / 5, kk = f - mt * 5;
      int lane = idx >> 3, j = idx & 7;
      int wr = mt * 16 + (lane & 15);
      int k  = kk * 32 + (lane >> 4) * 8 + j;     // 0..159
      float v = 0.f;
      if (k < 80) {
        int kb = k;
        if (kb <= 64) {
          float sn, cs; sincosf((TWOPI / 128.f) * (float)((wr * kb) & 127), &sn, &cs);
          v = SC * ((kb == 0 || kb == 64) ? 1.f : 2.f) * cs;
        }
      } else {
        int kb = k - 80;                           // imag of bins 0,64 ignored (c2r)
        if (kb >= 1 && kb <= 63) {
          float sn, cs; sincosf((TWOPI / 128.f) * (float)((wr * kb) & 127), &sn, &cs);
          v = -2.f * SC * sn;
        }
      }
      wf[TWI_OFF + (size_t)f * 512 + idx] = f2bf(v);
    }
  }
}

// ================= k_fft_w: rfft along W via GEMM, x -> packed A =================
__global__ __launch_bounds__(256) void k_fft_w(const float* __restrict__ x,
                                               unsigned int* __restrict__ A,
                                               const unsigned short* __restrict__ wf) {
  __shared__ unsigned short Xt[64 * 136];          // [ch][r] bf16
  const int h = blockIdx.x, c0 = blockIdx.y * 64, b = blockIdx.z, t = threadIdx.x;
  const int wv = t >> 6, lane = t & 63, l15 = lane & 15, lg = lane >> 4;
  const float* xp = x + ((size_t)(b * HH + h)) * WW * HD + c0;
  for (int idx = t; idx < 128 * 64; idx += 256) {
    int r = idx >> 6, ch = idx & 63;
    Xt[ch * 136 + r] = f2bf(xp[(size_t)r * HD + ch]);
  }
  __syncthreads();
  const unsigned short* tw = wf + TW_OFF;
  f32x4 acc[10];
#pragma unroll
  for (int m = 0; m < 10; ++m) acc[m] = { 0.f, 0.f, 0.f, 0.f };
#pragma unroll
  for (int kk = 0; kk < 4; ++kk) {
    short8 bq = *(const short8*)&Xt[(wv * 16 + l15) * 136 + kk * 32 + lg * 8];
#pragma unroll
    for (int m = 0; m < 10; ++m) {
      short8 a = *(const short8*)&tw[(size_t)(m * 4 + kk) * 512 + lane * 8];
      acc[m] = MFMA(a, bq, acc[m], 0, 0, 0);
    }
  }
  unsigned int* Ao = A + ((size_t)b * NPOS + h * WC) * HD + c0 + wv * 16 + l15;
#pragma unroll
  for (int q = 0; q < 5; ++q)
#pragma unroll
    for (int r = 0; r < 4; ++r) {
      int ko = q * 16 + lg * 4 + r;
      if (ko <= 64) Ao[(size_t)ko * HD] = pack2(acc[q][r], acc[5 + q][r]);
    }
}

// ================= k_ifft_w: irfft along W via GEMM + bias =================
__global__ __launch_bounds__(256) void k_ifft_w(const unsigned int* __restrict__ A,
                                                const float* __restrict__ x,
                                                float* __restrict__ out,
                                                const unsigned short* __restrict__ wf) {
  __shared__ unsigned short Zt[64 * 168];          // [ch][k-stack 160]
  const int h = blockIdx.x, c0 = blockIdx.y * 64, b = blockIdx.z, t = threadIdx.x;
  const int wv = t >> 6, lane = t & 63, l15 = lane & 15, lg = lane >> 4;
  const unsigned int* Ai = A + ((size_t)b * NPOS + h * WC) * HD + c0;
  for (int idx = t; idx < 65 * 64; idx += 256) {
    int kb = idx >> 6, ch = idx & 63;
    unsigned int u = Ai[(size_t)kb * HD + ch];
    Zt[ch * 168 + kb]      = (unsigned short)(u & 0xffffu);
    Zt[ch * 168 + 80 + kb] = (unsigned short)(u >> 16);
  }
  for (int idx = t; idx < 64 * 32; idx += 256) {   // zero-pad k 65..79 both halves
    int ch = idx >> 5, q = idx & 31;
    if (q < 30) {
      int kb = 65 + (q % 15), half = q / 15;
      Zt[ch * 168 + half * 80 + kb] = 0;
    }
  }
  __syncthreads();
  const unsigned short* twi = wf + TWI_OFF;
  f32x4 acc[8];
#pragma unroll
  for (int m = 0; m < 8; ++m) acc[m] = { 0.f, 0.f, 0.f, 0.f };
#pragma unroll
  for (int kk = 0; kk < 5; ++kk) {
    short8 bq = *(const short8*)&Zt[(wv * 16 + l15) * 168 + kk * 32 + lg * 8];
#pragma unroll
    for (int m = 0; m < 8; ++m) {
      short8 a = *(const short8*)&twi[(size_t)(m * 5 + kk) * 512 + lane * 8];
      acc[m] = MFMA(a, bq, acc[m], 0, 0, 0);
    }
  }
#pragma unroll
  for (int m = 0; m < 8; ++m)
#pragma unroll
    for (int r = 0; r < 4; ++r) {
      int wr = m * 16 + lg * 4 + r;
      size_t go = (((size_t)(b * HH + h)) * WW + wr) * HD + c0 + wv * 16 + l15;
      out[go] = acc[m][r] + x[go];
    }
}

// ================= k_mid: H-DFT fwd + MLP + softshrink + H-DFT inv =================
static __device__ inline short8 afragq(const unsigned int* Zq, int row, int k0) {
  const unsigned int* z = Zq + row * 100 + (k0 < 96 ? k0 : k0 - 96);
  uint4 a = *(const uint4*)z, b = *(const uint4*)(z + 4);
  return (k0 < 96) ? lo8(a, b) : hi8(a, b);
}

// complex 128-DFT GEMM on separate R/I bf16 LDS arrays [ch][r] (stride 136).
// parts: Ac=cos*SC, As=sin*SC, An=-sin*SC.
// FWD:  Re = Ac*R + As*I ; Im = Ac*I + An*R
// INV:  Re = Ac*R + An*I ; Im = Ac*I + As*R
template <int FWD>
static __device__ inline void dft_gemm(const unsigned short* Rb, const unsigned short* Ib,
                                       const unsigned short* tm, int w, int lane,
                                       f32x4* aR, f32x4* aI) {
  const int l15 = lane & 15, lg = lane >> 4;
#pragma unroll
  for (int kkr = 0; kkr < 4; ++kkr) {
    const int r0 = kkr * 32 + lg * 8;
    short8 Ac = *(const short8*)&tm[(size_t)(0 * 32 + w * 4 + kkr) * 512 + lane * 8];
    short8 As = *(const short8*)&tm[(size_t)(1 * 32 + w * 4 + kkr) * 512 + lane * 8];
    short8 An = *(const short8*)&tm[(size_t)(2 * 32 + w * 4 + kkr) * 512 + lane * 8];
#pragma unroll
    for (int co = 0; co < 6; ++co) {
      short8 zr = *(const short8*)&Rb[(co * 16 + l15) * 136 + r0];
      short8 zi = *(const short8*)&Ib[(co * 16 + l15) * 136 + r0];
      if constexpr (FWD) {
        aR[co] = MFMA(Ac, zr, aR[co], 0, 0, 0);
        aR[co] = MFMA(As, zi, aR[co], 0, 0, 0);
        aI[co] = MFMA(Ac, zi, aI[co], 0, 0, 0);
        aI[co] = MFMA(An, zr, aI[co], 0, 0, 0);
      } else {
        aR[co] = MFMA(Ac, zr, aR[co], 0, 0, 0);
        aR[co] = MFMA(An, zi, aR[co], 0, 0, 0);
        aI[co] = MFMA(Ac, zi, aI[co], 0, 0, 0);
        aI[co] = MFMA(As, zr, aI[co], 0, 0, 0);
      }
    }
  }
}

__global__ __launch_bounds__(512) void k_mid(unsigned int* __restrict__ A,
                                             const unsigned short* __restrict__ wf,
                                             const float* __restrict__ bpk) {
  __shared__ unsigned short Ub[2 * 13312];         // 53.2 KB, morphs per phase
  unsigned short* Rb = Ub;                         // [ch][r] / [ch][ko], stride 136
  unsigned short* Ib = Ub + 13312;
  unsigned int* Zq = (unsigned int*)Ub;            // [pos][ch] packed, stride 100

  const int kv = blockIdx.x, n = blockIdx.y, b = blockIdx.z, t = threadIdx.x;
  const int wid = t >> 6, lane = t & 63, l15 = lane & 15, lg = lane >> 4;
  unsigned int* Abase = A + ((size_t)b * NPOS + kv) * HD + n * 96;
  const unsigned short* tm = wf + TM_OFF;

  // ---- stage: packed global -> separate R/I [ch][r]
  for (int idx = t; idx < 128 * 96; idx += 512) {
    int r = idx / 96, ch = idx - r * 96;
    unsigned int u = Abase[(size_t)r * (WC * HD) + ch];
    Rb[ch * 136 + r] = (unsigned short)(u & 0xffffu);
    Ib[ch * 136 + r] = (unsigned short)(u >> 16);
  }
  __syncthreads();

  // ---- GEMM-1: forward H-DFT
  f32x4 aR[6], aI[6];
#pragma unroll
  for (int co = 0; co < 6; ++co) { aR[co] = {0.f,0.f,0.f,0.f}; aI[co] = {0.f,0.f,0.f,0.f}; }
  dft_gemm<1>(Rb, Ib, tm, wid, lane, aR, aI);
  __syncthreads();                                  // all R/I reads done
  // write packed Zq[pos][ch] (own 16-row strip; MLP reads only own strip -> no barrier)
#pragma unroll
  for (int co = 0; co < 6; ++co)
#pragma unroll
    for (int r = 0; r < 4; ++r)
      Zq[(wid * 16 + lg * 4 + r) * 100 + co * 16 + l15] = pack2(aR[co][r], aI[co][r]);

  // ---- MLP layer 1 (B-frags direct from L2-hot global, full bake)
  const unsigned short* wf1 = wf + WF_OFF + (size_t)n * (72 * 512);
  const unsigned short* wf2 = wf + WF_OFF + (size_t)(8 + n) * (72 * 512);
  f32x4 acc[12];
#pragma unroll
  for (int nt = 0; nt < 12; ++nt) {
    float bv = bpk[n * 192 + nt * 16 + l15];
    acc[nt] = { bv, bv, bv, bv };
  }
#pragma unroll
  for (int kk = 0; kk < 6; ++kk) {
    short8 a = afragq(Zq, wid * 16 + l15, kk * 32 + lg * 8);
#pragma unroll
    for (int nt = 0; nt < 12; ++nt) {
      short8 bfr = *(const short8*)&wf1[(size_t)(kk * 12 + nt) * 512 + lane * 8];
      acc[nt] = MFMA(a, bfr, acc[nt], 0, 0, 0);
    }
  }
  // relu -> own rows of Zq
#pragma unroll
  for (int nt = 0; nt < 6; ++nt)
#pragma unroll
    for (int r = 0; r < 4; ++r)
      Zq[(wid * 16 + lg * 4 + r) * 100 + nt * 16 + l15] =
          pack2(fmaxf(acc[nt][r], 0.f), fmaxf(acc[nt + 6][r], 0.f));

  // ---- MLP layer 2
#pragma unroll
  for (int nt = 0; nt < 12; ++nt) {
    float bv = bpk[(8 + n) * 192 + nt * 16 + l15];
    acc[nt] = { bv, bv, bv, bv };
  }
#pragma unroll
  for (int kk = 0; kk < 6; ++kk) {
    short8 a = afragq(Zq, wid * 16 + l15, kk * 32 + lg * 8);
#pragma unroll
    for (int nt = 0; nt < 12; ++nt) {
      short8 bfr = *(const short8*)&wf2[(size_t)(kk * 12 + nt) * 512 + lane * 8];
      acc[nt] = MFMA(a, bfr, acc[nt], 0, 0, 0);
    }
  }
  __syncthreads();                                  // all Zq reads done before overwrite

  // ---- softshrink + write R/I [ch][ko] (natural ko order)
#pragma unroll
  for (int r = 0; r < 4; ++r) {
    int ko = wid * 16 + lg * 4 + r;
    float kus = (ko >= 64) ? (float)(ko - 128) : (float)ko;
    float k2v = kus * kus + (float)(kv * kv);
    float thr = fmaxf(0.01f * expf(-0.00125f * k2v), 0.0005f);
#pragma unroll
    for (int nt = 0; nt < 6; ++nt) {
      float mr = acc[nt][r], mi = acc[nt + 6][r];
      float mag = sqrtf(mr * mr + mi * mi + 1e-8f);
      float sf = fmaxf(mag - thr, 0.f) / mag;
      Rb[(nt * 16 + l15) * 136 + ko] = f2bf(mr * sf);
      Ib[(nt * 16 + l15) * 136 + ko] = f2bf(mi * sf);
    }
  }
  __syncthreads();

  // ---- GEMM-2: inverse H-DFT, write straight to global
#pragma unroll
  for (int co = 0; co < 6; ++co) { aR[co] = {0.f,0.f,0.f,0.f}; aI[co] = {0.f,0.f,0.f,0.f}; }
  dft_gemm<0>(Rb, Ib, tm, wid, lane, aR, aI);
#pragma unroll
  for (int co = 0; co < 6; ++co)
#pragma unroll
    for (int r = 0; r < 4; ++r) {
      int rr = wid * 16 + lg * 4 + r;
      Abase[(size_t)rr * (WC * HD) + co * 16 + l15] = pack2(aR[co][r], aI[co][r]);
    }
}

extern "C" void kernel_launch(void* const* d_in, const int* in_sizes, int n_in,
                              void* d_out, int out_size, void* d_ws, size_t ws_size,
                              hipStream_t stream) {
  const float* x  = (const float*)d_in[0];
  const float* w1 = (const float*)d_in[1];
  const float* b1 = (const float*)d_in[2];
  const float* w2 = (const float*)d_in[3];
  const float* b2 = (const float*)d_in[4];
  float* out = (float*)d_out;
  unsigned int* A = (unsigned int*)d_ws;            // 102.2 MB spectral plane

  // baked tables in d_ws right after A (~1.4 MB) — no kernel writes near them
  unsigned short* wf = (unsigned short*)(A + A_UINTS);
  float* bpk = (float*)(wf + WF_END_U16);

  k_prep<<<19, 256, 0, stream>>>(w1, b1, w2, b2, wf, bpk);
  k_fft_w<<<dim3(HH, HD / 64, 4), 256, 0, stream>>>(x, A, wf);
  k_mid<<<dim3(WC, NBLK, 4), 512, 0, stream>>>(A, wf, bpk);
  k_ifft_w<<<dim3(HH, HD / 64, 4), 256, 0, stream>>>(A, x, out, wf);
}

// Round 9
// 462.283 us; speedup vs baseline: 1.3520x; 1.3520x over previous
//
#include <hip/hip_runtime.h>
#include <hip/hip_bf16.h>
#include <math.h>

// AFNO2D: rfft2(128x128, ortho) -> blockdiag complex MLP (8 x 96) -> softshrink -> irfft2 -> +bias
// B=4, H=W=128, C=768.  ALL transforms are MFMA GEMMs against baked bf16 matrices (tables in d_ws
// after the A plane). Spectral plane in ws: packed uint per point (bf16 re | bf16 im<<16),
// A[b][pos=h*65+kw][c].
// k_mid v3: 1024 threads (16 waves = 4/SIMD at 88KB LDS), R/I-split bf16 LDS (raw short8 MFMA
// operands, no unpack VALU), WfL dedup'd weight frags staged in LDS (round-8 global-read
// regression reverted). 16-wave task split: GEMMs = 8 ko-tiles x 2 co-halves; MLP = strip pair
// splits nt {0-2,6-8}/{3-5,9-11} so softshrink (re,im) pairs stay wave-local.

#define HD   768
#define NBLK 8
#define HH   128
#define WW   128
#define WC   65
#define NPOS (HH * WC)

constexpr float SC    = 0.08838834764831845f;      // 1/sqrt(128)
constexpr float TWOPI = 6.28318530717958647692f;

// table layout (ushort offsets from wf base)
constexpr int TM_OFF     = 0;        // H-DFT: 96 frags = part(3:cos,sin,-sin) x kot(8) x kk(4)
constexpr int TW_OFF     = 49152;    // W-rfft: 40 frags = mt(10) x kk(4)
constexpr int TWI_OFF    = 69632;    // W-irfft: 40 frags = mt(8) x kk(5)
constexpr int WF_OFF     = 90112;    // MLP: 16 (layer,n) x 72 frags (full bake; k_mid stages first 36)
constexpr int WF_END_U16 = 679936;   // WF_OFF + 16*72*512
constexpr size_t A_UINTS = (size_t)4 * NPOS * HD;  // 102.2 MB

typedef __attribute__((ext_vector_type(8))) short short8;
typedef __attribute__((ext_vector_type(4))) float f32x4;

#define MFMA __builtin_amdgcn_mfma_f32_16x16x32_bf16

static __device__ inline unsigned short f2bf(float f) {
  __hip_bfloat16 h = __float2bfloat16(f);
  return __builtin_bit_cast(unsigned short, h);
}
static __device__ inline unsigned int pack2(float re, float im) {
  return (unsigned int)f2bf(re) | ((unsigned int)f2bf(im) << 16);
}

// ================= k_prep: bake all MFMA fragment images =================
// A-frag: lane holds A[row = tile*16 + (l&15)][k = kk*32 + (l>>4)*8 + j]
// B-frag: lane holds B[k = kk*32 + (l>>4)*8 + j][col = nt*16 + (l&15)]
__global__ __launch_bounds__(256) void k_prep(const float* __restrict__ w1,
                                              const float* __restrict__ b1,
                                              const float* __restrict__ w2,
                                              const float* __restrict__ b2,
                                              unsigned short* __restrict__ wf,
                                              float* __restrict__ bpk) {
  const int blk = blockIdx.x, t = threadIdx.x;
  if (blk < 16) {                      // MLP Waug B-frags (full 72) + biases
    const int layer = blk >> 3, n = blk & 7;
    const float* w  = layer ? w2 : w1;
    const float* bs = layer ? b2 : b1;
    unsigned short* dst = wf + WF_OFF + (size_t)blk * (72 * 512);
    for (int e = t; e < 72 * 512; e += 256) {
      int f = e >> 9, idx = e & 511;
      int kk = f / 12, nt = f - kk * 12;
      int lane = idx >> 3, j = idx & 7;
      int k  = kk * 32 + (lane >> 4) * 8 + j;     // 0..191
      int cc = nt * 16 + (lane & 15);             // 0..191
      float v;
      if (k < 96) v = (cc < 96) ? w[(size_t)n * 9216 + k * 96 + cc]
                                : w[(size_t)(8 + n) * 9216 + k * 96 + (cc - 96)];
      else        v = (cc < 96) ? -w[(size_t)(8 + n) * 9216 + (k - 96) * 96 + cc]
                                :  w[(size_t)n * 9216 + (k - 96) * 96 + (cc - 96)];
      dst[e] = f2bf(v);
    }
    for (int c = t; c < 192; c += 256)
      bpk[blk * 192 + c] = (c < 96) ? bs[n * 96 + c] : bs[(8 + n) * 96 + (c - 96)];
  } else if (blk == 16) {              // H-DFT twiddles: 3 parts x 32 (kot*4+kk)
    for (int e = t; e < 96 * 512; e += 256) {
      int f = e >> 9, idx = e & 511;
      int part = f >> 5, rem = f & 31, kot = rem >> 2, kk = rem & 3;
      int lane = idx >> 3, j = idx & 7;
      int ko = kot * 16 + (lane & 15);
      int r  = kk * 32 + (lane >> 4) * 8 + j;     // 0..127
      float sn, cs; sincosf((TWOPI / 128.f) * (float)((ko * r) & 127), &sn, &cs);
      float v = (part == 0) ? cs : (part == 1) ? sn : -sn;
      wf[TM_OFF + (size_t)f * 512 + idx] = f2bf(v * SC);
    }
  } else if (blk == 17) {              // W-rfft matrix: rows 0..79 = re, 80..159 = im
    for (int e = t; e < 40 * 512; e += 256) {
      int f = e >> 9, idx = e & 511;
      int mt = f >> 2, kk = f & 3;
      int lane = idx >> 3, j = idx & 7;
      int row = mt * 16 + (lane & 15);
      int r   = kk * 32 + (lane >> 4) * 8 + j;    // 0..127
      int kor = (row < 80) ? row : row - 80;
      float sn, cs; sincosf((TWOPI / 128.f) * (float)((kor * r) & 127), &sn, &cs);
      wf[TW_OFF + (size_t)f * 512 + idx] = f2bf((row < 80 ? cs : -sn) * SC);
    }
  } else {                             // W-irfft matrix: K = [re 0..79 | im 0..79]
    for (int e = t; e < 40 * 512; e += 256) {
      int f = e >> 9, idx = e & 511;
      int mt = f / 5, kk = f - mt * 5;
      int lane = idx >> 3, j = idx & 7;
      int wr = mt * 16 + (lane & 15);
      int k  = kk * 32 + (lane >> 4) * 8 + j;     // 0..159
      float v = 0.f;
      if (k < 80) {
        int kb = k;
        if (kb <= 64) {
          float sn, cs; sincosf((TWOPI / 128.f) * (float)((wr * kb) & 127), &sn, &cs);
          v = SC * ((kb == 0 || kb == 64) ? 1.f : 2.f) * cs;
        }
      } else {
        int kb = k - 80;                           // imag of bins 0,64 ignored (c2r)
        if (kb >= 1 && kb <= 63) {
          float sn, cs; sincosf((TWOPI / 128.f) * (float)((wr * kb) & 127), &sn, &cs);
          v = -2.f * SC * sn;
        }
      }
      wf[TWI_OFF + (size_t)f * 512 + idx] = f2bf(v);
    }
  }
}

// ================= k_fft_w: rfft along W via GEMM, x -> packed A =================
__global__ __launch_bounds__(256) void k_fft_w(const float* __restrict__ x,
                                               unsigned int* __restrict__ A,
                                               const unsigned short* __restrict__ wf) {
  __shared__ unsigned short Xt[64 * 136];          // [ch][r] bf16
  const int h = blockIdx.x, c0 = blockIdx.y * 64, b = blockIdx.z, t = threadIdx.x;
  const int wv = t >> 6, lane = t & 63, l15 = lane & 15, lg = lane >> 4;
  const float* xp = x + ((size_t)(b * HH + h)) * WW * HD + c0;
  for (int idx = t; idx < 128 * 64; idx += 256) {
    int r = idx >> 6, ch = idx & 63;
    Xt[ch * 136 + r] = f2bf(xp[(size_t)r * HD + ch]);
  }
  __syncthreads();
  const unsigned short* tw = wf + TW_OFF;
  f32x4 acc[10];
#pragma unroll
  for (int m = 0; m < 10; ++m) acc[m] = { 0.f, 0.f, 0.f, 0.f };
#pragma unroll
  for (int kk = 0; kk < 4; ++kk) {
    short8 bq = *(const short8*)&Xt[(wv * 16 + l15) * 136 + kk * 32 + lg * 8];
#pragma unroll
    for (int m = 0; m < 10; ++m) {
      short8 a = *(const short8*)&tw[(size_t)(m * 4 + kk) * 512 + lane * 8];
      acc[m] = MFMA(a, bq, acc[m], 0, 0, 0);
    }
  }
  unsigned int* Ao = A + ((size_t)b * NPOS + h * WC) * HD + c0 + wv * 16 + l15;
#pragma unroll
  for (int q = 0; q < 5; ++q)
#pragma unroll
    for (int r = 0; r < 4; ++r) {
      int ko = q * 16 + lg * 4 + r;
      if (ko <= 64) Ao[(size_t)ko * HD] = pack2(acc[q][r], acc[5 + q][r]);
    }
}

// ================= k_ifft_w: irfft along W via GEMM + bias =================
__global__ __launch_bounds__(256) void k_ifft_w(const unsigned int* __restrict__ A,
                                                const float* __restrict__ x,
                                                float* __restrict__ out,
                                                const unsigned short* __restrict__ wf) {
  __shared__ unsigned short Zt[64 * 168];          // [ch][k-stack 160]
  const int h = blockIdx.x, c0 = blockIdx.y * 64, b = blockIdx.z, t = threadIdx.x;
  const int wv = t >> 6, lane = t & 63, l15 = lane & 15, lg = lane >> 4;
  const unsigned int* Ai = A + ((size_t)b * NPOS + h * WC) * HD + c0;
  for (int idx = t; idx < 65 * 64; idx += 256) {
    int kb = idx >> 6, ch = idx & 63;
    unsigned int u = Ai[(size_t)kb * HD + ch];
    Zt[ch * 168 + kb]      = (unsigned short)(u & 0xffffu);
    Zt[ch * 168 + 80 + kb] = (unsigned short)(u >> 16);
  }
  for (int idx = t; idx < 64 * 32; idx += 256) {   // zero-pad k 65..79 both halves
    int ch = idx >> 5, q = idx & 31;
    if (q < 30) {
      int kb = 65 + (q % 15), half = q / 15;
      Zt[ch * 168 + half * 80 + kb] = 0;
    }
  }
  __syncthreads();
  const unsigned short* twi = wf + TWI_OFF;
  f32x4 acc[8];
#pragma unroll
  for (int m = 0; m < 8; ++m) acc[m] = { 0.f, 0.f, 0.f, 0.f };
#pragma unroll
  for (int kk = 0; kk < 5; ++kk) {
    short8 bq = *(const short8*)&Zt[(wv * 16 + l15) * 168 + kk * 32 + lg * 8];
#pragma unroll
    for (int m = 0; m < 8; ++m) {
      short8 a = *(const short8*)&twi[(size_t)(m * 5 + kk) * 512 + lane * 8];
      acc[m] = MFMA(a, bq, acc[m], 0, 0, 0);
    }
  }
#pragma unroll
  for (int m = 0; m < 8; ++m)
#pragma unroll
    for (int r = 0; r < 4; ++r) {
      int wr = m * 16 + lg * 4 + r;
      size_t go = (((size_t)(b * HH + h)) * WW + wr) * HD + c0 + wv * 16 + l15;
      out[go] = acc[m][r] + x[go];
    }
}

// ================= k_mid: H-DFT fwd + MLP + softshrink + H-DFT inv (16 waves) =========
// LDS plane union: GEMM phases use [ch 0..95][r 0..127] stride 136; MLP phase uses
// [pos 0..127][ch 0..95] stride 104. Both fit in 13312 ushorts per R/I array.
template <int FWD>
static __device__ inline void dft_gemm16(const unsigned short* Rb, const unsigned short* Ib,
                                         const unsigned short* tm, int rt, int cb, int lane,
                                         f32x4* aR, f32x4* aI) {
  const int l15 = lane & 15, lg = lane >> 4;
#pragma unroll
  for (int kkr = 0; kkr < 4; ++kkr) {
    const int r0 = kkr * 32 + lg * 8;
    short8 Ac = *(const short8*)&tm[(size_t)(0 * 32 + rt * 4 + kkr) * 512 + lane * 8];
    short8 As = *(const short8*)&tm[(size_t)(1 * 32 + rt * 4 + kkr) * 512 + lane * 8];
    short8 An = *(const short8*)&tm[(size_t)(2 * 32 + rt * 4 + kkr) * 512 + lane * 8];
#pragma unroll
    for (int c = 0; c < 3; ++c) {
      short8 zr = *(const short8*)&Rb[((cb + c) * 16 + l15) * 136 + r0];
      short8 zi = *(const short8*)&Ib[((cb + c) * 16 + l15) * 136 + r0];
      aR[c] = MFMA(Ac, zr, aR[c], 0, 0, 0);
      if constexpr (FWD) {
        aR[c] = MFMA(As, zi, aR[c], 0, 0, 0);
        aI[c] = MFMA(Ac, zi, aI[c], 0, 0, 0);
        aI[c] = MFMA(An, zr, aI[c], 0, 0, 0);
      } else {
        aR[c] = MFMA(An, zi, aR[c], 0, 0, 0);
        aI[c] = MFMA(Ac, zi, aI[c], 0, 0, 0);
        aI[c] = MFMA(As, zr, aI[c], 0, 0, 0);
      }
    }
  }
}

__global__ __launch_bounds__(1024) void k_mid(unsigned int* __restrict__ A,
                                              const unsigned short* __restrict__ wf,
                                              const float* __restrict__ bpk) {
  __shared__ unsigned short Rb[13312], Ib[13312];  // 53.2 KB plane (layout morphs)
  __shared__ unsigned short WfL[36 * 512];         // 36.9 KB dedup'd weight frags
  const int kv = blockIdx.x, n = blockIdx.y, b = blockIdx.z, t = threadIdx.x;
  const int w = t >> 6, lane = t & 63, l15 = lane & 15, lg = lane >> 4;
  const int rt = w >> 1, cb = (w & 1) * 3;         // ko/row tile 0..7, co-half base
  unsigned int* Abase = A + ((size_t)b * NPOS + kv) * HD + n * 96;
  const unsigned short* tm = wf + TM_OFF;

  // ---- stage packed global -> R/I [ch][r]  +  layer-1 frags (first 36 = kk 0..2)
  for (int idx = t; idx < 128 * 96; idx += 1024) {
    int r = idx / 96, ch = idx - r * 96;
    unsigned int u = Abase[(size_t)r * (WC * HD) + ch];
    Rb[ch * 136 + r] = (unsigned short)(u & 0xffffu);
    Ib[ch * 136 + r] = (unsigned short)(u >> 16);
  }
  {
    const int4* s1 = (const int4*)(wf + WF_OFF + (size_t)n * (72 * 512));
    for (int idx = t; idx < 2304; idx += 1024) ((int4*)WfL)[idx] = s1[idx];
  }
  __syncthreads();                                  // B1

  // ---- GEMM-1: forward H-DFT (wave: ko-tile rt, co = cb..cb+2)
  f32x4 aR[3], aI[3];
#pragma unroll
  for (int c = 0; c < 3; ++c) { aR[c] = {0.f,0.f,0.f,0.f}; aI[c] = {0.f,0.f,0.f,0.f}; }
  dft_gemm16<1>(Rb, Ib, tm, rt, cb, lane, aR, aI);
  __syncthreads();                                  // B2: all [ch][r] reads done
#pragma unroll
  for (int c = 0; c < 3; ++c)
#pragma unroll
    for (int r = 0; r < 4; ++r) {
      int row = rt * 16 + lg * 4 + r, ch = (cb + c) * 16 + l15;
      Rb[row * 104 + ch] = f2bf(aR[c][r]);
      Ib[row * 104 + ch] = f2bf(aI[c][r]);
    }
  __syncthreads();                                  // B3: [pos][ch] writes visible

  // ---- MLP layer 1: strip rt, nts {cb..cb+2} U {cb+6..cb+8}
  const int row_a = (rt * 16 + l15) * 104;
  f32x4 acc[6];
#pragma unroll
  for (int i = 0; i < 3; ++i) {
    float bv = bpk[n * 192 + (cb + i) * 16 + l15];
    acc[i] = { bv, bv, bv, bv };
    bv = bpk[n * 192 + (cb + i + 6) * 16 + l15];
    acc[3 + i] = { bv, bv, bv, bv };
  }
#pragma unroll
  for (int kk = 0; kk < 6; ++kk) {
    short8 a = (kk < 3) ? *(const short8*)&Rb[row_a + kk * 32 + lg * 8]
                        : *(const short8*)&Ib[row_a + (kk - 3) * 32 + lg * 8];
#pragma unroll
    for (int i = 0; i < 6; ++i) {
      int nt = cb + (i < 3 ? i : i + 3);
      short8 bfr;
      if (kk < 3) bfr = *(const short8*)&WfL[(kk * 12 + nt) * 512 + lane * 8];
      else {
        int nt2 = (nt < 6) ? nt + 6 : nt - 6;
        int4 nb = *(const int4*)&WfL[((kk - 3) * 12 + nt2) * 512 + lane * 8];
        if (nt < 6) { nb.x ^= 0x80008000; nb.y ^= 0x80008000; nb.z ^= 0x80008000; nb.w ^= 0x80008000; }
        bfr = __builtin_bit_cast(short8, nb);
      }
      acc[i] = MFMA(a, bfr, acc[i], 0, 0, 0);
    }
  }
  __syncthreads();                                  // B4: L1 compute done (WfL + plane reads)
  // relu -> [pos][ch] (strip rt, own ch half)
#pragma unroll
  for (int i = 0; i < 3; ++i)
#pragma unroll
    for (int r = 0; r < 4; ++r) {
      int row = rt * 16 + lg * 4 + r, ch = (cb + i) * 16 + l15;
      Rb[row * 104 + ch] = f2bf(fmaxf(acc[i][r], 0.f));
      Ib[row * 104 + ch] = f2bf(fmaxf(acc[3 + i][r], 0.f));
    }
  {
    const int4* s2 = (const int4*)(wf + WF_OFF + (size_t)(8 + n) * (72 * 512));
    for (int idx = t; idx < 2304; idx += 1024) ((int4*)WfL)[idx] = s2[idx];
  }
  __syncthreads();                                  // B5

  // ---- MLP layer 2
#pragma unroll
  for (int i = 0; i < 3; ++i) {
    float bv = bpk[(8 + n) * 192 + (cb + i) * 16 + l15];
    acc[i] = { bv, bv, bv, bv };
    bv = bpk[(8 + n) * 192 + (cb + i + 6) * 16 + l15];
    acc[3 + i] = { bv, bv, bv, bv };
  }
#pragma unroll
  for (int kk = 0; kk < 6; ++kk) {
    short8 a = (kk < 3) ? *(const short8*)&Rb[row_a + kk * 32 + lg * 8]
                        : *(const short8*)&Ib[row_a + (kk - 3) * 32 + lg * 8];
#pragma unroll
    for (int i = 0; i < 6; ++i) {
      int nt = cb + (i < 3 ? i : i + 3);
      short8 bfr;
      if (kk < 3) bfr = *(const short8*)&WfL[(kk * 12 + nt) * 512 + lane * 8];
      else {
        int nt2 = (nt < 6) ? nt + 6 : nt - 6;
        int4 nb = *(const int4*)&WfL[((kk - 3) * 12 + nt2) * 512 + lane * 8];
        if (nt < 6) { nb.x ^= 0x80008000; nb.y ^= 0x80008000; nb.z ^= 0x80008000; nb.w ^= 0x80008000; }
        bfr = __builtin_bit_cast(short8, nb);
      }
      acc[i] = MFMA(a, bfr, acc[i], 0, 0, 0);
    }
  }
  __syncthreads();                                  // B6: L2 plane reads done

  // ---- softshrink -> [ch][ko]
#pragma unroll
  for (int r = 0; r < 4; ++r) {
    int ko = rt * 16 + lg * 4 + r;
    float kus = (ko >= 64) ? (float)(ko - 128) : (float)ko;
    float k2v = kus * kus + (float)(kv * kv);
    float thr = fmaxf(0.01f * expf(-0.00125f * k2v), 0.0005f);
#pragma unroll
    for (int i = 0; i < 3; ++i) {
      float mr = acc[i][r], mi = acc[3 + i][r];
      float mag = sqrtf(mr * mr + mi * mi + 1e-8f);
      float sf = fmaxf(mag - thr, 0.f) / mag;
      int ch = (cb + i) * 16 + l15;
      Rb[ch * 136 + ko] = f2bf(mr * sf);
      Ib[ch * 136 + ko] = f2bf(mi * sf);
    }
  }
  __syncthreads();                                  // B7

  // ---- GEMM-2: inverse H-DFT, write straight to global
#pragma unroll
  for (int c = 0; c < 3; ++c) { aR[c] = {0.f,0.f,0.f,0.f}; aI[c] = {0.f,0.f,0.f,0.f}; }
  dft_gemm16<0>(Rb, Ib, tm, rt, cb, lane, aR, aI);
#pragma unroll
  for (int c = 0; c < 3; ++c)
#pragma unroll
    for (int r = 0; r < 4; ++r) {
      int rr = rt * 16 + lg * 4 + r, ch = (cb + c) * 16 + l15;
      Abase[(size_t)rr * (WC * HD) + ch] = pack2(aR[c][r], aI[c][r]);
    }
}

extern "C" void kernel_launch(void* const* d_in, const int* in_sizes, int n_in,
                              void* d_out, int out_size, void* d_ws, size_t ws_size,
                              hipStream_t stream) {
  const float* x  = (const float*)d_in[0];
  const float* w1 = (const float*)d_in[1];
  const float* b1 = (const float*)d_in[2];
  const float* w2 = (const float*)d_in[3];
  const float* b2 = (const float*)d_in[4];
  float* out = (float*)d_out;
  unsigned int* A = (unsigned int*)d_ws;            // 102.2 MB spectral plane

  // baked tables in d_ws right after A (~1.4 MB) — no kernel writes near them
  unsigned short* wf = (unsigned short*)(A + A_UINTS);
  float* bpk = (float*)(wf + WF_END_U16);

  k_prep<<<19, 256, 0, stream>>>(w1, b1, w2, b2, wf, bpk);
  k_fft_w<<<dim3(HH, HD / 64, 4), 256, 0, stream>>>(x, A, wf);
  k_mid<<<dim3(WC, NBLK, 4), 1024, 0, stream>>>(A, wf, bpk);
  k_ifft_w<<<dim3(HH, HD / 64, 4), 256, 0, stream>>>(A, x, out, wf);
}